// Round 14
// baseline (7441.393 us; speedup 1.0000x reference)
//
#include <hip/hip_runtime.h>

// Problem constants (DownSampling: B=16, N=16384, C=128, M=N/4=4096)
// Device buffers: FLOAT32 in/out. Oracle = jax expected, computed with
// XLA:GPU (ROCm) on this chip class. XLA GPU sets FPOpFusion::Fast; algsimp
// unrolls the size-3 reduce into an expression TREE (dx^2+dy^2)+dz^2 with
// no zero-init; LLVM's DAG contract rule fuses operand-0's mul of each fadd:
//   inner = fma(dx,dx, rn(dy*dy))      // dy^2 rounded, dx*dx unrounded
//   d     = fma(dz,dz, inner)
// This is 1-ulp-adjacent to the exact cluster E (R1/R2/R6), matching the
// observed O<->E distance (~one near-tie flip), and is the only natural
// compiler-generated variant not yet tested.
#define B_   16
#define N_   16384
#define C_   128
#define M_   4096
#define TPB  1024
#define PPT  16   // points per thread: TPB*PPT == N_

// -------------------------------------------------------------------------
// FPS kernel: one block per batch. Each thread owns 16 consecutive points in
// registers (f32 x,y,z,dist). Per iteration:
//   d = fma(dz,dz, fma(dx,dx, rn(dy*dy)))   [XLA-GPU tree-contract order]
//   dist = min(dist, d)
// per-thread argmax (first-index ties), wave shfl butterfly argmax,
// cross-wave LDS reduce (double-buffered, single barrier), broadcast next
// centroid from global. Tie-break: smallest index at every level.
// -------------------------------------------------------------------------
__global__ __launch_bounds__(TPB, 4) void fps_kernel(const float* __restrict__ xyz,
                                                     int* __restrict__ idx_out)
{
    const int b = blockIdx.x;
    const int t = threadIdx.x;
    const int wid  = t >> 6;
    const int lane = t & 63;
    const float* xb = xyz + (size_t)b * 3 * N_;

    float px[PPT], py[PPT], pz[PPT], dist[PPT];

    // Load 16 consecutive points per thread (float4-vectorized, coalesced).
    {
        const float4* x4 = reinterpret_cast<const float4*>(xb);
        const float4* y4 = reinterpret_cast<const float4*>(xb + N_);
        const float4* z4 = reinterpret_cast<const float4*>(xb + 2 * N_);
        #pragma unroll
        for (int q = 0; q < 4; ++q) {
            float4 vx = x4[t * 4 + q];
            float4 vy = y4[t * 4 + q];
            float4 vz = z4[t * 4 + q];
            px[q*4+0] = vx.x; px[q*4+1] = vx.y; px[q*4+2] = vx.z; px[q*4+3] = vx.w;
            py[q*4+0] = vy.x; py[q*4+1] = vy.y; py[q*4+2] = vy.z; py[q*4+3] = vy.w;
            pz[q*4+0] = vz.x; pz[q*4+1] = vz.y; pz[q*4+2] = vz.z; pz[q*4+3] = vz.w;
        }
    }
    #pragma unroll
    for (int i = 0; i < PPT; ++i) dist[i] = 1e10f;  // BIG sentinel

    __shared__ float lv[2][16];
    __shared__ int   li[2][16];

    if (t == 0) idx_out[b * M_ + 0] = 0;   // deterministic start at index 0

    // First centroid = point 0.
    float cx = xb[0], cy = xb[N_], cz = xb[2 * N_];

    for (int m = 1; m < M_; ++m) {
        // ---- XLA-GPU tree-contract distance + per-thread argmax (first wins)
        float bmax = -1.0f;
        int bslot = 0;
        #pragma unroll
        for (int i = 0; i < PPT; ++i) {
            float dx = __fsub_rn(px[i], cx);
            float dy = __fsub_rn(py[i], cy);
            float dz = __fsub_rn(pz[i], cz);
            float inner = fmaf(dx, dx, __fmul_rn(dy, dy));
            float d     = fmaf(dz, dz, inner);
            float nd = fminf(dist[i], d);
            dist[i] = nd;
            bool c = nd > bmax;   // strict > => smallest slot wins ties
            bmax  = c ? nd : bmax;
            bslot = c ? i  : bslot;
        }
        int gidx = t * PPT + bslot;

        // ---- wave (64-lane) argmax reduce, tie -> smaller index
        #pragma unroll
        for (int off = 32; off >= 1; off >>= 1) {
            float ov = __shfl_xor(bmax, off);
            int   oi = __shfl_xor(gidx, off);
            bool take = (ov > bmax) || ((ov == bmax) && (oi < gidx));
            bmax = take ? ov : bmax;
            gidx = take ? oi : gidx;
        }

        // ---- cross-wave reduce via double-buffered LDS, single barrier
        const int buf = m & 1;
        if (lane == 0) { lv[buf][wid] = bmax; li[buf][wid] = gidx; }
        __syncthreads();
        float v  = (lane < 16) ? lv[buf][lane] : -1.0f;
        int   gi = (lane < 16) ? li[buf][lane] : 0x7fffffff;
        #pragma unroll
        for (int off = 8; off >= 1; off >>= 1) {
            float ov = __shfl_xor(v, off);
            int   oi = __shfl_xor(gi, off);
            bool take = (ov > v) || ((ov == v) && (oi < gi));
            v  = take ? ov : v;
            gi = take ? oi : gi;
        }
        int j = __shfl(gi, 0);   // every wave now knows the global argmax

        if (t == 0) idx_out[b * M_ + m] = j;

        // Next centroid: same-address broadcast load (L2-resident, 192KB/batch).
        cx = xb[j];
        cy = xb[N_ + j];
        cz = xb[2 * N_ + j];
    }
}

// -------------------------------------------------------------------------
// Gather kernel: one block per (batch, output row). Rows 0..2 = xyz, 3..130 =
// feature channels. Raw f32 passthrough of gathered values.
// -------------------------------------------------------------------------
__global__ void gather_kernel(const float* __restrict__ xyz,
                              const float* __restrict__ feat,
                              const int*   __restrict__ idx,
                              float*       __restrict__ out)
{
    const int blk = blockIdx.x;
    const int b = blk / (3 + C_);
    const int r = blk % (3 + C_);
    const int* idb = idx + b * M_;

    if (r < 3) {
        const float* src = xyz + ((size_t)b * 3 + r) * N_;
        float*       dst = out + ((size_t)b * 3 + r) * M_;
        for (int m = threadIdx.x; m < M_; m += blockDim.x)
            dst[m] = src[idb[m]];
    } else {
        const int c = r - 3;
        const float* src = feat + ((size_t)b * C_ + c) * N_;
        float*       dst = out + (size_t)B_ * 3 * M_ + ((size_t)b * C_ + c) * M_;
        for (int m = threadIdx.x; m < M_; m += blockDim.x)
            dst[m] = src[idb[m]];
    }
}

extern "C" void kernel_launch(void* const* d_in, const int* in_sizes, int n_in,
                              void* d_out, int out_size, void* d_ws, size_t ws_size,
                              hipStream_t stream)
{
    const float* xyz  = (const float*)d_in[0];   // [16, 3, 16384] f32
    const float* feat = (const float*)d_in[1];   // [16, 128, 16384] f32
    float* out = (float*)d_out;                  // [16*3*4096] + [16*128*4096] f32
    int*   idx = (int*)d_ws;                     // [16, 4096] int32 scratch

    fps_kernel<<<dim3(B_), dim3(TPB), 0, stream>>>(xyz, idx);
    gather_kernel<<<dim3(B_ * (3 + C_)), dim3(256), 0, stream>>>(xyz, feat, idx, out);
}